// Round 1
// baseline (129.533 us; speedup 1.0000x reference)
//
#include <hip/hip_runtime.h>

// ---------------------------------------------------------------------------
// FakeFusedMoE: E=8 experts, H=1024, F=1024, top-2, N=2048 tokens.
// Sparse (top-2 only) grouped-GEMM MoE with bf16 MFMA compute.
//
// Pipeline (all on `stream`):
//   k_convert_hidden : fp32 hidden -> bf16 (ws)
//   k_router         : logits -> top2 -> analytic renorm weights
//   k_build_perm     : counting-sort (token,k) pairs by expert
//   k_gemm1          : grouped GEMM [rows,H]x[H,2F] + fused SwiGLU -> act bf16
//   k_gemm2          : grouped GEMM [rows,F]x[F,H], weight in epilogue -> partial
//   k_combine        : out[n] = partial[2n] + partial[2n+1]
// ---------------------------------------------------------------------------

#define NTOK   2048
#define HDIM   1024
#define FDIM   1024
#define NEXP   8
#define NKROWS 4096   // NTOK * TOPK

typedef __attribute__((ext_vector_type(8))) __bf16 bf16x8;
typedef __attribute__((ext_vector_type(4))) float  floatx4;

// round-to-nearest-even fp32 -> bf16 (bit manipulation; no NaN inputs here)
__device__ __forceinline__ unsigned short f2bf(float x) {
    unsigned int u = __builtin_bit_cast(unsigned int, x);
    u += 0x7FFFu + ((u >> 16) & 1u);
    return (unsigned short)(u >> 16);
}

__device__ __forceinline__ uint4 pack8(float4 a, float4 b) {
    uint4 o;
    o.x = (unsigned)f2bf(a.x) | ((unsigned)f2bf(a.y) << 16);
    o.y = (unsigned)f2bf(a.z) | ((unsigned)f2bf(a.w) << 16);
    o.z = (unsigned)f2bf(b.x) | ((unsigned)f2bf(b.y) << 16);
    o.w = (unsigned)f2bf(b.z) | ((unsigned)f2bf(b.w) << 16);
    return o;
}

// XOR swizzle within a 128B LDS row (breaks 16-way ds_read_b128 bank conflict)
__device__ __forceinline__ int swz(int row, int byteoff) {
    return byteoff ^ ((row & 7) << 4);
}

// ---------------------------------------------------------------------------
__global__ __launch_bounds__(256) void k_convert_hidden(
    const float* __restrict__ h, unsigned short* __restrict__ hbf)
{
    int i = (blockIdx.x * 256 + threadIdx.x) * 8;   // grid covers N*H exactly
    const float4* src = reinterpret_cast<const float4*>(h + i);
    float4 a = src[0], b = src[1];
    *reinterpret_cast<uint4*>(hbf + i) = pack8(a, b);
}

// ---------------------------------------------------------------------------
__global__ __launch_bounds__(256) void k_router(
    const float* __restrict__ h, const float* __restrict__ rw,
    int* __restrict__ topk_idx, float* __restrict__ topk_w)
{
    const int lane = threadIdx.x & 63;
    const int wave = threadIdx.x >> 6;
    const int n = blockIdx.x * 4 + wave;

    const float4* hp = reinterpret_cast<const float4*>(h + (size_t)n * HDIM);
    float acc[NEXP];
#pragma unroll
    for (int e = 0; e < NEXP; ++e) acc[e] = 0.f;

#pragma unroll
    for (int i0 = 0; i0 < HDIM / 4; i0 += 64) {
        float4 hv = hp[i0 + lane];
#pragma unroll
        for (int e = 0; e < NEXP; ++e) {
            float4 rv = reinterpret_cast<const float4*>(rw + e * HDIM)[i0 + lane];
            acc[e] += hv.x * rv.x + hv.y * rv.y + hv.z * rv.z + hv.w * rv.w;
        }
    }
#pragma unroll
    for (int e = 0; e < NEXP; ++e) {
#pragma unroll
        for (int off = 32; off > 0; off >>= 1)
            acc[e] += __shfl_xor(acc[e], off);
    }
    if (lane == 0) {
        int i0 = 0; float m0 = acc[0];
        for (int e = 1; e < NEXP; ++e) if (acc[e] > m0) { m0 = acc[e]; i0 = e; }
        int i1 = -1; float m1 = -3.0e38f;
        for (int e = 0; e < NEXP; ++e) if (e != i0 && acc[e] > m1) { m1 = acc[e]; i1 = e; }
        // softmax -> top2 -> renorm == analytic from top-2 logits
        float d  = __expf(m1 - m0);
        float w0 = 1.f / (1.f + d);
        topk_idx[n * 2 + 0] = i0;
        topk_idx[n * 2 + 1] = i1;
        topk_w [n * 2 + 0] = w0;
        topk_w [n * 2 + 1] = 1.f - w0;
    }
}

// ---------------------------------------------------------------------------
__global__ __launch_bounds__(256) void k_build_perm(
    const int* __restrict__ topk_idx, const float* __restrict__ topk_w,
    int* __restrict__ offsets, int* __restrict__ perm_slot, float* __restrict__ row_w)
{
    __shared__ int cnt[NEXP];
    __shared__ int cur[NEXP];
    __shared__ int off[NEXP + 1];
    const int t = threadIdx.x;
    if (t < NEXP) cnt[t] = 0;
    __syncthreads();
    for (int s = t; s < NKROWS; s += 256) atomicAdd(&cnt[topk_idx[s]], 1);
    __syncthreads();
    if (t == 0) {
        int a = 0;
        for (int e = 0; e < NEXP; ++e) { off[e] = a; a += cnt[e]; cur[e] = off[e]; }
        off[NEXP] = a;
    }
    __syncthreads();
    for (int s = t; s < NKROWS; s += 256) {
        int e = topk_idx[s];
        int pos = atomicAdd(&cur[e], 1);
        perm_slot[pos] = s;
        row_w[pos] = topk_w[s];
    }
    if (t < NEXP + 1) offsets[t] = off[t];
}

// ---------------------------------------------------------------------------
// GEMM1: per expert, act[p][f] = silu(gate) * up, gate/up from gate_up_proj.
// Tile: 128 rows x 64 f-cols (gate AND up halves), BK=64, 4 waves (2x2).
__global__ __launch_bounds__(256) void k_gemm1(
    const unsigned short* __restrict__ hbf, const float* __restrict__ gu,
    const int* __restrict__ offsets, const int* __restrict__ perm_slot,
    unsigned short* __restrict__ act)
{
    const int e  = blockIdx.y >> 4;
    const int rt = blockIdx.y & 15;
    const int off_e = offsets[e];
    const int n_e   = offsets[e + 1] - off_e;
    if (rt * 128 >= n_e) return;
    const int p0 = off_e + rt * 128;
    const int nr = min(128, n_e - rt * 128);
    const int c0 = blockIdx.x * 64;

    __shared__ __align__(16) char smA[128 * 128];   // 128 rows x 64 bf16
    __shared__ __align__(16) char smBg[64 * 128];   // 64 cols x 64 bf16
    __shared__ __align__(16) char smBu[64 * 128];
    __shared__ int sTok[128];

    const int t = threadIdx.x;
    if (t < 128) sTok[t] = perm_slot[min(p0 + t, NKROWS - 1)] >> 1;

    const int lane = t & 63;
    const int wv = t >> 6;
    const int wr = wv >> 1, wc = wv & 1;

    floatx4 accg[4][2], accu[4][2];
#pragma unroll
    for (int m = 0; m < 4; ++m)
#pragma unroll
        for (int nn = 0; nn < 2; ++nn) {
            accg[m][nn] = (floatx4)0.f;
            accu[m][nn] = (floatx4)0.f;
        }

    const float* guE = gu + (size_t)e * (2 * FDIM) * HDIM;
    const int arow = t >> 1, ahalf = t & 1;
    const int bcol = t >> 2, bq = t & 3;

    for (int k0 = 0; k0 < HDIM; k0 += 64) {
        __syncthreads();
        {   // stage A (bf16 gather rows)
            const uint4* src = reinterpret_cast<const uint4*>(
                hbf + (size_t)sTok[arow] * HDIM + k0 + ahalf * 32);
            uint4 v0 = src[0], v1 = src[1], v2 = src[2], v3 = src[3];
            char* base = smA + arow * 128;
            int bo = ahalf * 64;
            *reinterpret_cast<uint4*>(base + swz(arow, bo +  0)) = v0;
            *reinterpret_cast<uint4*>(base + swz(arow, bo + 16)) = v1;
            *reinterpret_cast<uint4*>(base + swz(arow, bo + 32)) = v2;
            *reinterpret_cast<uint4*>(base + swz(arow, bo + 48)) = v3;
        }
        {   // stage B gate + up (fp32 -> bf16 in-register)
            const float* sg = guE + (size_t)(c0 + bcol) * HDIM + k0 + bq * 16;
            const float* su = guE + (size_t)(FDIM + c0 + bcol) * HDIM + k0 + bq * 16;
            const float4* sg4 = reinterpret_cast<const float4*>(sg);
            const float4* su4 = reinterpret_cast<const float4*>(su);
            float4 g0 = sg4[0], g1 = sg4[1], g2 = sg4[2], g3 = sg4[3];
            float4 u0 = su4[0], u1 = su4[1], u2 = su4[2], u3 = su4[3];
            char* bg = smBg + bcol * 128;
            char* bu = smBu + bcol * 128;
            int bo = bq * 32;
            *reinterpret_cast<uint4*>(bg + swz(bcol, bo +  0)) = pack8(g0, g1);
            *reinterpret_cast<uint4*>(bg + swz(bcol, bo + 16)) = pack8(g2, g3);
            *reinterpret_cast<uint4*>(bu + swz(bcol, bo +  0)) = pack8(u0, u1);
            *reinterpret_cast<uint4*>(bu + swz(bcol, bo + 16)) = pack8(u2, u3);
        }
        __syncthreads();
#pragma unroll
        for (int kk = 0; kk < 2; ++kk) {
            const int kbyte = kk * 64 + (lane >> 4) * 16;
            bf16x8 a[4], bg[2], bu[2];
#pragma unroll
            for (int m = 0; m < 4; ++m) {
                int row = wr * 64 + m * 16 + (lane & 15);
                a[m] = *reinterpret_cast<const bf16x8*>(smA + row * 128 + swz(row, kbyte));
            }
#pragma unroll
            for (int nn = 0; nn < 2; ++nn) {
                int cc = wc * 32 + nn * 16 + (lane & 15);
                bg[nn] = *reinterpret_cast<const bf16x8*>(smBg + cc * 128 + swz(cc, kbyte));
                bu[nn] = *reinterpret_cast<const bf16x8*>(smBu + cc * 128 + swz(cc, kbyte));
            }
#pragma unroll
            for (int m = 0; m < 4; ++m)
#pragma unroll
                for (int nn = 0; nn < 2; ++nn) {
                    accg[m][nn] = __builtin_amdgcn_mfma_f32_16x16x32_bf16(a[m], bg[nn], accg[m][nn], 0, 0, 0);
                    accu[m][nn] = __builtin_amdgcn_mfma_f32_16x16x32_bf16(a[m], bu[nn], accu[m][nn], 0, 0, 0);
                }
        }
    }
    // epilogue: silu(gate) * up -> act (bf16)
#pragma unroll
    for (int m = 0; m < 4; ++m)
#pragma unroll
        for (int nn = 0; nn < 2; ++nn)
#pragma unroll
            for (int j = 0; j < 4; ++j) {
                int rr = wr * 64 + m * 16 + ((lane >> 4) << 2) + j;
                if (rr < nr) {
                    int f = c0 + wc * 32 + nn * 16 + (lane & 15);
                    float g = accg[m][nn][j];
                    float u = accu[m][nn][j];
                    float s = g / (1.f + __expf(-g));
                    act[(size_t)(p0 + rr) * FDIM + f] = f2bf(s * u);
                }
            }
}

// ---------------------------------------------------------------------------
// GEMM2: per expert, partial[slot][h] = w * (act_row . down_proj[e][h][:])
__global__ __launch_bounds__(256) void k_gemm2(
    const unsigned short* __restrict__ act, const float* __restrict__ dp,
    const int* __restrict__ offsets, const int* __restrict__ perm_slot,
    const float* __restrict__ row_w, float* __restrict__ partial)
{
    const int e  = blockIdx.y >> 4;
    const int rt = blockIdx.y & 15;
    const int off_e = offsets[e];
    const int n_e   = offsets[e + 1] - off_e;
    if (rt * 128 >= n_e) return;
    const int p0 = off_e + rt * 128;
    const int nr = min(128, n_e - rt * 128);
    const int c0 = blockIdx.x * 64;   // output h columns

    __shared__ __align__(16) char smA[128 * 128];
    __shared__ __align__(16) char smB[64 * 128];
    __shared__ int   sSlot[128];
    __shared__ float sW[128];

    const int t = threadIdx.x;
    if (t < 128) {
        int p = min(p0 + t, NKROWS - 1);
        sSlot[t] = perm_slot[p];
        sW[t]    = row_w[p];
    }

    const int lane = t & 63;
    const int wv = t >> 6;
    const int wr = wv >> 1, wc = wv & 1;

    floatx4 acc[4][2];
#pragma unroll
    for (int m = 0; m < 4; ++m)
#pragma unroll
        for (int nn = 0; nn < 2; ++nn) acc[m][nn] = (floatx4)0.f;

    const float* dpE = dp + (size_t)e * HDIM * FDIM;
    const int arow = t >> 1, ahalf = t & 1;
    const int bcol = t >> 2, bq = t & 3;

    for (int k0 = 0; k0 < FDIM; k0 += 64) {
        __syncthreads();
        {   // stage A from act (contiguous rows, no gather)
            int p = min(p0 + arow, NKROWS - 1);
            const uint4* src = reinterpret_cast<const uint4*>(
                act + (size_t)p * FDIM + k0 + ahalf * 32);
            uint4 v0 = src[0], v1 = src[1], v2 = src[2], v3 = src[3];
            char* base = smA + arow * 128;
            int bo = ahalf * 64;
            *reinterpret_cast<uint4*>(base + swz(arow, bo +  0)) = v0;
            *reinterpret_cast<uint4*>(base + swz(arow, bo + 16)) = v1;
            *reinterpret_cast<uint4*>(base + swz(arow, bo + 32)) = v2;
            *reinterpret_cast<uint4*>(base + swz(arow, bo + 48)) = v3;
        }
        {   // stage B from down_proj (fp32 -> bf16)
            const float* sb = dpE + (size_t)(c0 + bcol) * FDIM + k0 + bq * 16;
            const float4* sb4 = reinterpret_cast<const float4*>(sb);
            float4 b0 = sb4[0], b1 = sb4[1], b2 = sb4[2], b3 = sb4[3];
            char* bb = smB + bcol * 128;
            int bo = bq * 32;
            *reinterpret_cast<uint4*>(bb + swz(bcol, bo +  0)) = pack8(b0, b1);
            *reinterpret_cast<uint4*>(bb + swz(bcol, bo + 16)) = pack8(b2, b3);
        }
        __syncthreads();
#pragma unroll
        for (int kk = 0; kk < 2; ++kk) {
            const int kbyte = kk * 64 + (lane >> 4) * 16;
            bf16x8 a[4], b[2];
#pragma unroll
            for (int m = 0; m < 4; ++m) {
                int row = wr * 64 + m * 16 + (lane & 15);
                a[m] = *reinterpret_cast<const bf16x8*>(smA + row * 128 + swz(row, kbyte));
            }
#pragma unroll
            for (int nn = 0; nn < 2; ++nn) {
                int cc = wc * 32 + nn * 16 + (lane & 15);
                b[nn] = *reinterpret_cast<const bf16x8*>(smB + cc * 128 + swz(cc, kbyte));
            }
#pragma unroll
            for (int m = 0; m < 4; ++m)
#pragma unroll
                for (int nn = 0; nn < 2; ++nn)
                    acc[m][nn] = __builtin_amdgcn_mfma_f32_16x16x32_bf16(a[m], b[nn], acc[m][nn], 0, 0, 0);
        }
    }
#pragma unroll
    for (int m = 0; m < 4; ++m)
#pragma unroll
        for (int nn = 0; nn < 2; ++nn)
#pragma unroll
            for (int j = 0; j < 4; ++j) {
                int rr = wr * 64 + m * 16 + ((lane >> 4) << 2) + j;
                if (rr < nr) {
                    int hcol = c0 + wc * 32 + nn * 16 + (lane & 15);
                    partial[(size_t)sSlot[rr] * HDIM + hcol] = sW[rr] * acc[m][nn][j];
                }
            }
}

// ---------------------------------------------------------------------------
__global__ __launch_bounds__(256) void k_combine(
    const float* __restrict__ partial, float* __restrict__ out)
{
    int gid = blockIdx.x * 256 + threadIdx.x;   // 524288 = NTOK * H/4
    int n = gid >> 8;          // token
    int r = gid & 255;         // float4 index within row (H/4 = 256)
    const float4* pp = reinterpret_cast<const float4*>(partial);
    float4 a = pp[(size_t)(2 * n)     * 256 + r];
    float4 b = pp[(size_t)(2 * n + 1) * 256 + r];
    float4 o;
    o.x = a.x + b.x; o.y = a.y + b.y; o.z = a.z + b.z; o.w = a.w + b.w;
    reinterpret_cast<float4*>(out)[(size_t)n * 256 + r] = o;
}

// ---------------------------------------------------------------------------
extern "C" void kernel_launch(void* const* d_in, const int* in_sizes, int n_in,
                              void* d_out, int out_size, void* d_ws, size_t ws_size,
                              hipStream_t stream)
{
    const float* h  = (const float*)d_in[0];   // [2,1024,1024]
    const float* rw = (const float*)d_in[1];   // [8,1024]
    const float* gu = (const float*)d_in[2];   // [8,2048,1024]
    const float* dp = (const float*)d_in[3];   // [8,1024,1024]
    float* out = (float*)d_out;

    char* ws = (char*)d_ws;
    int*            topk_idx  = (int*)   (ws + 0);
    float*          topk_w    = (float*) (ws + 16384);
    int*            offsets   = (int*)   (ws + 32768);
    int*            perm_slot = (int*)   (ws + 36864);
    float*          row_w     = (float*) (ws + 53248);
    unsigned short* hbf       = (unsigned short*)(ws + (1u << 20));
    unsigned short* act       = (unsigned short*)(ws + (8u << 20));
    float*          partial   = (float*) (ws + (16u << 20));

    hipLaunchKernelGGL(k_convert_hidden, dim3(1024), dim3(256), 0, stream, h, hbf);
    hipLaunchKernelGGL(k_router,         dim3(512),  dim3(256), 0, stream, h, rw, topk_idx, topk_w);
    hipLaunchKernelGGL(k_build_perm,     dim3(1),    dim3(256), 0, stream, topk_idx, topk_w, offsets, perm_slot, row_w);
    hipLaunchKernelGGL(k_gemm1,          dim3(16, 128), dim3(256), 0, stream, hbf, gu, offsets, perm_slot, act);
    hipLaunchKernelGGL(k_gemm2,          dim3(16, 128), dim3(256), 0, stream, act, dp, offsets, perm_slot, row_w, partial);
    hipLaunchKernelGGL(k_combine,        dim3(2048), dim3(256), 0, stream, partial, out);
}

// Round 2
// 114.865 us; speedup vs baseline: 1.1277x; 1.1277x over previous
//
#include <hip/hip_runtime.h>

// ---------------------------------------------------------------------------
// FakeFusedMoE: E=8, H=1024, F=1024, top-2, N=2048 tokens (4096 routed rows).
// Sparse grouped-GEMM MoE, bf16 MFMA, 2-phase pipelined (dbuf LDS + early
// issue + global_load_lds for the bf16 A operands).
// ---------------------------------------------------------------------------

#define NTOK   2048
#define HDIM   1024
#define FDIM   1024
#define NEXP   8
#define NKROWS 4096

typedef __attribute__((ext_vector_type(8))) __bf16 bf16x8;
typedef __attribute__((ext_vector_type(4))) float  floatx4;

__device__ __forceinline__ unsigned short f2bf(float x) {
    unsigned int u = __builtin_bit_cast(unsigned int, x);
    u += 0x7FFFu + ((u >> 16) & 1u);
    return (unsigned short)(u >> 16);
}

__device__ __forceinline__ uint4 pack8(float4 a, float4 b) {
    uint4 o;
    o.x = (unsigned)f2bf(a.x) | ((unsigned)f2bf(a.y) << 16);
    o.y = (unsigned)f2bf(a.z) | ((unsigned)f2bf(a.w) << 16);
    o.z = (unsigned)f2bf(b.x) | ((unsigned)f2bf(b.y) << 16);
    o.w = (unsigned)f2bf(b.z) | ((unsigned)f2bf(b.w) << 16);
    return o;
}

// XOR swizzle within a 128B LDS row (kills 16-way ds_read_b128 conflicts)
__device__ __forceinline__ int swz(int row, int byteoff) {
    return byteoff ^ ((row & 7) << 4);
}

// async global->LDS, 16B per lane; LDS dest is wave-uniform base + lane*16
__device__ __forceinline__ void dma16(const void* g, void* l) {
    __builtin_amdgcn_global_load_lds(
        (const __attribute__((address_space(1))) unsigned int*)g,
        (__attribute__((address_space(3))) unsigned int*)l, 16, 0, 0);
}

// ---------------------------------------------------------------------------
// Router fused with fp32->bf16 hidden conversion. One wave per token.
__global__ __launch_bounds__(256) void k_router(
    const float* __restrict__ h, const float* __restrict__ rw,
    unsigned short* __restrict__ hbf,
    int* __restrict__ topk_idx, float* __restrict__ topk_w)
{
    const int lane = threadIdx.x & 63;
    const int wave = threadIdx.x >> 6;
    const int n = blockIdx.x * 4 + wave;

    const float4* hp = reinterpret_cast<const float4*>(h + (size_t)n * HDIM);
    uint2* hb = reinterpret_cast<uint2*>(hbf + (size_t)n * HDIM);
    float acc[NEXP];
#pragma unroll
    for (int e = 0; e < NEXP; ++e) acc[e] = 0.f;

#pragma unroll
    for (int i0 = 0; i0 < HDIM / 4; i0 += 64) {
        float4 hv = hp[i0 + lane];
        uint2 o;
        o.x = (unsigned)f2bf(hv.x) | ((unsigned)f2bf(hv.y) << 16);
        o.y = (unsigned)f2bf(hv.z) | ((unsigned)f2bf(hv.w) << 16);
        hb[i0 + lane] = o;
#pragma unroll
        for (int e = 0; e < NEXP; ++e) {
            float4 rv = reinterpret_cast<const float4*>(rw + e * HDIM)[i0 + lane];
            acc[e] += hv.x * rv.x + hv.y * rv.y + hv.z * rv.z + hv.w * rv.w;
        }
    }
#pragma unroll
    for (int e = 0; e < NEXP; ++e) {
#pragma unroll
        for (int off = 32; off > 0; off >>= 1)
            acc[e] += __shfl_xor(acc[e], off);
    }
    if (lane == 0) {
        int i0 = 0; float m0 = acc[0];
        for (int e = 1; e < NEXP; ++e) if (acc[e] > m0) { m0 = acc[e]; i0 = e; }
        int i1 = -1; float m1 = -3.0e38f;
        for (int e = 0; e < NEXP; ++e) if (e != i0 && acc[e] > m1) { m1 = acc[e]; i1 = e; }
        float d  = __expf(m1 - m0);
        float w0 = 1.f / (1.f + d);
        topk_idx[n * 2 + 0] = i0;
        topk_idx[n * 2 + 1] = i1;
        topk_w [n * 2 + 0] = w0;
        topk_w [n * 2 + 1] = 1.f - w0;
    }
}

// ---------------------------------------------------------------------------
__global__ __launch_bounds__(256) void k_build_perm(
    const int* __restrict__ topk_idx, const float* __restrict__ topk_w,
    int* __restrict__ offsets, int* __restrict__ perm_slot, float* __restrict__ row_w)
{
    __shared__ int cnt[NEXP];
    __shared__ int cur[NEXP];
    __shared__ int off[NEXP + 1];
    const int t = threadIdx.x;
    if (t < NEXP) cnt[t] = 0;
    __syncthreads();
    for (int s = t; s < NKROWS; s += 256) atomicAdd(&cnt[topk_idx[s]], 1);
    __syncthreads();
    if (t == 0) {
        int a = 0;
        for (int e = 0; e < NEXP; ++e) { off[e] = a; a += cnt[e]; cur[e] = off[e]; }
        off[NEXP] = a;
    }
    __syncthreads();
    for (int s = t; s < NKROWS; s += 256) {
        int e = topk_idx[s];
        int pos = atomicAdd(&cur[e], 1);
        perm_slot[pos] = s;
        row_w[pos] = topk_w[s];
    }
    if (t < NEXP + 1) offsets[t] = off[t];
}

// ---------------------------------------------------------------------------
// GEMM1: act[p][f] = silu(gate)*up. Tile 128 rows x 64 f-cols, BK=64, 4 waves,
// double-buffered LDS, A via global_load_lds (pre-swizzled source), B fp32
// reg-staged one step early with in-register bf16 conversion.
__global__ __launch_bounds__(256, 2) void k_gemm1(
    const unsigned short* __restrict__ hbf, const float* __restrict__ gu,
    const int* __restrict__ offsets, const int* __restrict__ perm_slot,
    unsigned short* __restrict__ act)
{
    const int e  = blockIdx.y >> 4;
    const int rt = blockIdx.y & 15;
    const int off_e = offsets[e];
    const int n_e   = offsets[e + 1] - off_e;
    if (rt * 128 >= n_e) return;
    const int p0 = off_e + rt * 128;
    const int nr = min(128, n_e - rt * 128);
    const int c0 = blockIdx.x * 64;

    __shared__ __align__(16) char smA [2][128 * 128];
    __shared__ __align__(16) char smBg[2][64 * 128];
    __shared__ __align__(16) char smBu[2][64 * 128];
    __shared__ int sTok[128];

    const int t = threadIdx.x;
    const int lane = t & 63;
    const int wv = t >> 6;
    const int wr = wv >> 1, wc = wv & 1;
    if (t < 128) sTok[t] = perm_slot[min(p0 + t, NKROWS - 1)] >> 1;
    __syncthreads();

    // A-DMA: wave wv owns chunks ch=wv*4+c (8 rows each). lane -> row ch*8+(lane>>3),
    // source byte pre-swizzled so linear LDS dest holds the swizzled layout.
    const int rin = lane >> 3;
    const char* asrc[4];
    int aldso[4];
#pragma unroll
    for (int c = 0; c < 4; ++c) {
        int ch = wv * 4 + c;
        int row = ch * 8 + rin;
        asrc[c] = (const char*)(hbf + (size_t)sTok[row] * HDIM)
                  + (((lane & 7) << 4) ^ (rin << 4));
        aldso[c] = ch * 1024;
    }

    const int bcol = t >> 2, bq = t & 3;
    const float* gsrc = gu + (size_t)e * (2 * FDIM) * HDIM + (size_t)(c0 + bcol) * HDIM + bq * 16;
    const float* usrc = gsrc + (size_t)FDIM * HDIM;

    floatx4 accg[4][2], accu[4][2];
#pragma unroll
    for (int m = 0; m < 4; ++m)
#pragma unroll
        for (int nn = 0; nn < 2; ++nn) { accg[m][nn] = (floatx4)0.f; accu[m][nn] = (floatx4)0.f; }

    float4 g[4], u[4];
    // ---- prologue: stage step 0 into buf 0
#pragma unroll
    for (int c = 0; c < 4; ++c) dma16(asrc[c], &smA[0][aldso[c]]);
#pragma unroll
    for (int q = 0; q < 4; ++q) {
        g[q] = reinterpret_cast<const float4*>(gsrc)[q];
        u[q] = reinterpret_cast<const float4*>(usrc)[q];
    }
    {
        char* bg = &smBg[0][bcol * 128];
        char* bu = &smBu[0][bcol * 128];
        int bo = bq * 32;
        *reinterpret_cast<uint4*>(bg + swz(bcol, bo))      = pack8(g[0], g[1]);
        *reinterpret_cast<uint4*>(bg + swz(bcol, bo + 16)) = pack8(g[2], g[3]);
        *reinterpret_cast<uint4*>(bu + swz(bcol, bo))      = pack8(u[0], u[1]);
        *reinterpret_cast<uint4*>(bu + swz(bcol, bo + 16)) = pack8(u[2], u[3]);
    }
    __syncthreads();

    int cur = 0;
    for (int step = 0; step < 16; ++step) {
        if (step < 15) {               // issue next K-step's traffic early
            int k0 = (step + 1) * 64;
#pragma unroll
            for (int c = 0; c < 4; ++c) dma16(asrc[c] + k0 * 2, &smA[cur ^ 1][aldso[c]]);
            const float4* gp = reinterpret_cast<const float4*>(gsrc + k0);
            const float4* up = reinterpret_cast<const float4*>(usrc + k0);
#pragma unroll
            for (int q = 0; q < 4; ++q) { g[q] = gp[q]; u[q] = up[q]; }
        }
        // compute current buffer
#pragma unroll
        for (int kk = 0; kk < 2; ++kk) {
            const int kbyte = kk * 64 + (lane >> 4) * 16;
            bf16x8 a[4], fg[2], fu[2];
#pragma unroll
            for (int m = 0; m < 4; ++m) {
                int row = wr * 64 + m * 16 + (lane & 15);
                a[m] = *reinterpret_cast<const bf16x8*>(&smA[cur][row * 128 + swz(row, kbyte)]);
            }
#pragma unroll
            for (int nn = 0; nn < 2; ++nn) {
                int cc = wc * 32 + nn * 16 + (lane & 15);
                fg[nn] = *reinterpret_cast<const bf16x8*>(&smBg[cur][cc * 128 + swz(cc, kbyte)]);
                fu[nn] = *reinterpret_cast<const bf16x8*>(&smBu[cur][cc * 128 + swz(cc, kbyte)]);
            }
#pragma unroll
            for (int m = 0; m < 4; ++m)
#pragma unroll
                for (int nn = 0; nn < 2; ++nn) {
                    accg[m][nn] = __builtin_amdgcn_mfma_f32_16x16x32_bf16(a[m], fg[nn], accg[m][nn], 0, 0, 0);
                    accu[m][nn] = __builtin_amdgcn_mfma_f32_16x16x32_bf16(a[m], fu[nn], accu[m][nn], 0, 0, 0);
                }
        }
        if (step < 15) {               // commit next buffer, one barrier/iter
            char* bg = &smBg[cur ^ 1][bcol * 128];
            char* bu = &smBu[cur ^ 1][bcol * 128];
            int bo = bq * 32;
            *reinterpret_cast<uint4*>(bg + swz(bcol, bo))      = pack8(g[0], g[1]);
            *reinterpret_cast<uint4*>(bg + swz(bcol, bo + 16)) = pack8(g[2], g[3]);
            *reinterpret_cast<uint4*>(bu + swz(bcol, bo))      = pack8(u[0], u[1]);
            *reinterpret_cast<uint4*>(bu + swz(bcol, bo + 16)) = pack8(u[2], u[3]);
            __syncthreads();
            cur ^= 1;
        }
    }

    // epilogue: silu(gate) * up -> act (bf16)
#pragma unroll
    for (int m = 0; m < 4; ++m)
#pragma unroll
        for (int nn = 0; nn < 2; ++nn)
#pragma unroll
            for (int j = 0; j < 4; ++j) {
                int rr = wr * 64 + m * 16 + ((lane >> 4) << 2) + j;
                if (rr < nr) {
                    int f = c0 + wc * 32 + nn * 16 + (lane & 15);
                    float gg = accg[m][nn][j];
                    float uu = accu[m][nn][j];
                    float s = gg / (1.f + __expf(-gg));
                    act[(size_t)(p0 + rr) * FDIM + f] = f2bf(s * uu);
                }
            }
}

// ---------------------------------------------------------------------------
// GEMM2: partial[slot][h] = w * (act_row . dp[e][h][:]). Same pipeline shape.
__global__ __launch_bounds__(256, 2) void k_gemm2(
    const unsigned short* __restrict__ act, const float* __restrict__ dp,
    const int* __restrict__ offsets, const int* __restrict__ perm_slot,
    const float* __restrict__ row_w, float* __restrict__ partial)
{
    const int e  = blockIdx.y >> 4;
    const int rt = blockIdx.y & 15;
    const int off_e = offsets[e];
    const int n_e   = offsets[e + 1] - off_e;
    if (rt * 128 >= n_e) return;
    const int p0 = off_e + rt * 128;
    const int nr = min(128, n_e - rt * 128);
    const int c0 = blockIdx.x * 64;

    __shared__ __align__(16) char smA[2][128 * 128];
    __shared__ __align__(16) char smB[2][64 * 128];
    __shared__ int   sSlot[128];
    __shared__ float sW[128];

    const int t = threadIdx.x;
    const int lane = t & 63;
    const int wv = t >> 6;
    const int wr = wv >> 1, wc = wv & 1;
    if (t < 128) {
        int p = min(p0 + t, NKROWS - 1);
        sSlot[t] = perm_slot[p];
        sW[t]    = row_w[p];
    }

    const int rin = lane >> 3;
    const char* asrc[4];
    int aldso[4];
#pragma unroll
    for (int c = 0; c < 4; ++c) {
        int ch = wv * 4 + c;
        int row = ch * 8 + rin;
        int p = min(p0 + row, NKROWS - 1);
        asrc[c] = (const char*)(act + (size_t)p * FDIM)
                  + (((lane & 7) << 4) ^ (rin << 4));
        aldso[c] = ch * 1024;
    }

    const int bcol = t >> 2, bq = t & 3;
    const float* bsrc = dp + (size_t)e * HDIM * FDIM + (size_t)(c0 + bcol) * FDIM + bq * 16;

    floatx4 acc[4][2];
#pragma unroll
    for (int m = 0; m < 4; ++m)
#pragma unroll
        for (int nn = 0; nn < 2; ++nn) acc[m][nn] = (floatx4)0.f;

    float4 b[4];
    // prologue
#pragma unroll
    for (int c = 0; c < 4; ++c) dma16(asrc[c], &smA[0][aldso[c]]);
#pragma unroll
    for (int q = 0; q < 4; ++q) b[q] = reinterpret_cast<const float4*>(bsrc)[q];
    {
        char* bb = &smB[0][bcol * 128];
        int bo = bq * 32;
        *reinterpret_cast<uint4*>(bb + swz(bcol, bo))      = pack8(b[0], b[1]);
        *reinterpret_cast<uint4*>(bb + swz(bcol, bo + 16)) = pack8(b[2], b[3]);
    }
    __syncthreads();

    int cur = 0;
    for (int step = 0; step < 16; ++step) {
        if (step < 15) {
            int k0 = (step + 1) * 64;
#pragma unroll
            for (int c = 0; c < 4; ++c) dma16(asrc[c] + k0 * 2, &smA[cur ^ 1][aldso[c]]);
            const float4* bp = reinterpret_cast<const float4*>(bsrc + k0);
#pragma unroll
            for (int q = 0; q < 4; ++q) b[q] = bp[q];
        }
#pragma unroll
        for (int kk = 0; kk < 2; ++kk) {
            const int kbyte = kk * 64 + (lane >> 4) * 16;
            bf16x8 a[4], fb[2];
#pragma unroll
            for (int m = 0; m < 4; ++m) {
                int row = wr * 64 + m * 16 + (lane & 15);
                a[m] = *reinterpret_cast<const bf16x8*>(&smA[cur][row * 128 + swz(row, kbyte)]);
            }
#pragma unroll
            for (int nn = 0; nn < 2; ++nn) {
                int cc = wc * 32 + nn * 16 + (lane & 15);
                fb[nn] = *reinterpret_cast<const bf16x8*>(&smB[cur][cc * 128 + swz(cc, kbyte)]);
            }
#pragma unroll
            for (int m = 0; m < 4; ++m)
#pragma unroll
                for (int nn = 0; nn < 2; ++nn)
                    acc[m][nn] = __builtin_amdgcn_mfma_f32_16x16x32_bf16(a[m], fb[nn], acc[m][nn], 0, 0, 0);
        }
        if (step < 15) {
            char* bb = &smB[cur ^ 1][bcol * 128];
            int bo = bq * 32;
            *reinterpret_cast<uint4*>(bb + swz(bcol, bo))      = pack8(b[0], b[1]);
            *reinterpret_cast<uint4*>(bb + swz(bcol, bo + 16)) = pack8(b[2], b[3]);
            __syncthreads();
            cur ^= 1;
        }
    }

#pragma unroll
    for (int m = 0; m < 4; ++m)
#pragma unroll
        for (int nn = 0; nn < 2; ++nn)
#pragma unroll
            for (int j = 0; j < 4; ++j) {
                int rr = wr * 64 + m * 16 + ((lane >> 4) << 2) + j;
                if (rr < nr) {
                    int hcol = c0 + wc * 32 + nn * 16 + (lane & 15);
                    partial[(size_t)sSlot[rr] * HDIM + hcol] = sW[rr] * acc[m][nn][j];
                }
            }
}

// ---------------------------------------------------------------------------
__global__ __launch_bounds__(256) void k_combine(
    const float* __restrict__ partial, float* __restrict__ out)
{
    int gid = blockIdx.x * 256 + threadIdx.x;
    int n = gid >> 8;
    int r = gid & 255;
    const float4* pp = reinterpret_cast<const float4*>(partial);
    float4 a = pp[(size_t)(2 * n)     * 256 + r];
    float4 b = pp[(size_t)(2 * n + 1) * 256 + r];
    float4 o;
    o.x = a.x + b.x; o.y = a.y + b.y; o.z = a.z + b.z; o.w = a.w + b.w;
    reinterpret_cast<float4*>(out)[(size_t)n * 256 + r] = o;
}

// ---------------------------------------------------------------------------
extern "C" void kernel_launch(void* const* d_in, const int* in_sizes, int n_in,
                              void* d_out, int out_size, void* d_ws, size_t ws_size,
                              hipStream_t stream)
{
    const float* h  = (const float*)d_in[0];
    const float* rw = (const float*)d_in[1];
    const float* gu = (const float*)d_in[2];
    const float* dp = (const float*)d_in[3];
    float* out = (float*)d_out;

    char* ws = (char*)d_ws;
    int*            topk_idx  = (int*)   (ws + 0);
    float*          topk_w    = (float*) (ws + 16384);
    int*            offsets   = (int*)   (ws + 32768);
    int*            perm_slot = (int*)   (ws + 36864);
    float*          row_w     = (float*) (ws + 53248);
    unsigned short* hbf       = (unsigned short*)(ws + (1u << 20));
    unsigned short* act       = (unsigned short*)(ws + (8u << 20));
    float*          partial   = (float*) (ws + (16u << 20));

    hipLaunchKernelGGL(k_router,     dim3(512),     dim3(256), 0, stream, h, rw, hbf, topk_idx, topk_w);
    hipLaunchKernelGGL(k_build_perm, dim3(1),       dim3(256), 0, stream, topk_idx, topk_w, offsets, perm_slot, row_w);
    hipLaunchKernelGGL(k_gemm1,      dim3(16, 128), dim3(256), 0, stream, hbf, gu, offsets, perm_slot, act);
    hipLaunchKernelGGL(k_gemm2,      dim3(16, 128), dim3(256), 0, stream, act, dp, offsets, perm_slot, row_w, partial);
    hipLaunchKernelGGL(k_combine,    dim3(2048),    dim3(256), 0, stream, partial, out);
}

// Round 3
// 89.152 us; speedup vs baseline: 1.4530x; 1.2884x over previous
//
#include <hip/hip_runtime.h>

// ---------------------------------------------------------------------------
// FakeFusedMoE: E=8, H=1024, F=1024, top-2, N=2048 tokens (4096 routed rows).
// Sparse grouped-GEMM MoE, bf16 MFMA. m97-structure GEMMs: single-buffered
// LDS, 2 barriers/K-step, ALL operands staged via global_load_lds (B staged
// as fp32, converted to bf16 at LDS-read time). 3-4 resident blocks/CU give
// cross-block latency overlap (m114 mechanism).
// ---------------------------------------------------------------------------

#define NTOK   2048
#define HDIM   1024
#define FDIM   1024
#define NEXP   8
#define NKROWS 4096
#define MAXTILES 40   // sum ceil(n_e/128) <= 39

typedef __attribute__((ext_vector_type(8))) __bf16 bf16x8;
typedef __attribute__((ext_vector_type(4))) float  floatx4;

__device__ __forceinline__ unsigned short f2bf(float x) {
    unsigned int u = __builtin_bit_cast(unsigned int, x);
    u += 0x7FFFu + ((u >> 16) & 1u);
    return (unsigned short)(u >> 16);
}

__device__ __forceinline__ float bf2f(unsigned short v) {
    unsigned int u = (unsigned int)v << 16;
    return __builtin_bit_cast(float, u);
}

// 8x fp32 -> bf16x8 fragment (compiler emits v_cvt_pk_bf16_f32 pairs)
__device__ __forceinline__ bf16x8 cvt8(float4 a, float4 b) {
    bf16x8 r;
    r[0] = (__bf16)a.x; r[1] = (__bf16)a.y; r[2] = (__bf16)a.z; r[3] = (__bf16)a.w;
    r[4] = (__bf16)b.x; r[5] = (__bf16)b.y; r[6] = (__bf16)b.z; r[7] = (__bf16)b.w;
    return r;
}

// async global->LDS, 16B/lane; LDS dest = wave-uniform base + lane*16
__device__ __forceinline__ void dma16(const void* g, void* l) {
    __builtin_amdgcn_global_load_lds(
        (const __attribute__((address_space(1))) unsigned int*)g,
        (__attribute__((address_space(3))) unsigned int*)l, 16, 0, 0);
}

// ---------------------------------------------------------------------------
// Router fused with fp32->bf16 hidden conversion. One wave per token.
__global__ __launch_bounds__(256) void k_router(
    const float* __restrict__ h, const float* __restrict__ rw,
    unsigned short* __restrict__ hbf,
    int* __restrict__ topk_idx, float* __restrict__ topk_w)
{
    const int lane = threadIdx.x & 63;
    const int wave = threadIdx.x >> 6;
    const int n = blockIdx.x * 4 + wave;

    const float4* hp = reinterpret_cast<const float4*>(h + (size_t)n * HDIM);
    uint2* hb = reinterpret_cast<uint2*>(hbf + (size_t)n * HDIM);
    float acc[NEXP];
#pragma unroll
    for (int e = 0; e < NEXP; ++e) acc[e] = 0.f;

#pragma unroll
    for (int i0 = 0; i0 < HDIM / 4; i0 += 64) {
        float4 hv = hp[i0 + lane];
        uint2 o;
        o.x = (unsigned)f2bf(hv.x) | ((unsigned)f2bf(hv.y) << 16);
        o.y = (unsigned)f2bf(hv.z) | ((unsigned)f2bf(hv.w) << 16);
        hb[i0 + lane] = o;
#pragma unroll
        for (int e = 0; e < NEXP; ++e) {
            float4 rv = reinterpret_cast<const float4*>(rw + e * HDIM)[i0 + lane];
            acc[e] += hv.x * rv.x + hv.y * rv.y + hv.z * rv.z + hv.w * rv.w;
        }
    }
#pragma unroll
    for (int e = 0; e < NEXP; ++e) {
#pragma unroll
        for (int off = 32; off > 0; off >>= 1)
            acc[e] += __shfl_xor(acc[e], off);
    }
    if (lane == 0) {
        int i0 = 0; float m0 = acc[0];
        for (int e = 1; e < NEXP; ++e) if (acc[e] > m0) { m0 = acc[e]; i0 = e; }
        int i1 = -1; float m1 = -3.0e38f;
        for (int e = 0; e < NEXP; ++e) if (e != i0 && acc[e] > m1) { m1 = acc[e]; i1 = e; }
        float d  = __expf(m1 - m0);
        float w0 = 1.f / (1.f + d);
        topk_idx[n * 2 + 0] = i0;
        topk_idx[n * 2 + 1] = i1;
        topk_w [n * 2 + 0] = w0;
        topk_w [n * 2 + 1] = 1.f - w0;
    }
}

// ---------------------------------------------------------------------------
// Counting-sort permutation + 128-row tile table.
__global__ __launch_bounds__(256) void k_build_perm(
    const int* __restrict__ topk_idx, const float* __restrict__ topk_w,
    int* __restrict__ offsets, int* __restrict__ perm_slot, float* __restrict__ row_w,
    int* __restrict__ tile_e, int* __restrict__ tile_rt)
{
    __shared__ int cnt[NEXP];
    __shared__ int cur[NEXP];
    __shared__ int off[NEXP + 1];
    const int t = threadIdx.x;
    if (t < NEXP) cnt[t] = 0;
    __syncthreads();
    for (int s = t; s < NKROWS; s += 256) atomicAdd(&cnt[topk_idx[s]], 1);
    __syncthreads();
    if (t == 0) {
        int a = 0;
        for (int e = 0; e < NEXP; ++e) { off[e] = a; a += cnt[e]; cur[e] = off[e]; }
        off[NEXP] = a;
        int nt = 0;
        for (int e = 0; e < NEXP; ++e) {
            int ne = cnt[e];
            for (int r = 0; r * 128 < ne; ++r) { tile_e[nt] = e; tile_rt[nt] = r; ++nt; }
        }
        for (; nt < MAXTILES; ++nt) { tile_e[nt] = -1; tile_rt[nt] = 0; }
    }
    __syncthreads();
    for (int s = t; s < NKROWS; s += 256) {
        int e = topk_idx[s];
        int pos = atomicAdd(&cur[e], 1);
        perm_slot[pos] = s;
        row_w[pos] = topk_w[s];
    }
    if (t < NEXP + 1) offsets[t] = off[t];
}

// ---------------------------------------------------------------------------
// GEMM1: act[p][f] = silu(gate)*up. Tile 128 rows x 64 f-cols (g AND u), BK=64,
// 4 waves (2x2, each 64rows x (32g+32u)). Single-buffer LDS, 2 barriers/step.
// A: bf16 via DMA (swizzled source). Bg/Bu: fp32 via DMA, cvt at read.
__global__ __launch_bounds__(256, 3) void k_gemm1(
    const unsigned short* __restrict__ hbf, const float* __restrict__ gu,
    const int* __restrict__ offsets, const int* __restrict__ perm_slot,
    const int* __restrict__ tile_e, const int* __restrict__ tile_rt,
    unsigned short* __restrict__ act)
{
    const int e = tile_e[blockIdx.y];
    if (e < 0) return;
    const int rt = tile_rt[blockIdx.y];
    const int off_e = offsets[e];
    const int n_e   = offsets[e + 1] - off_e;
    const int p0 = off_e + rt * 128;
    const int nr = min(128, n_e - rt * 128);
    const int c0 = blockIdx.x * 64;

    __shared__ __align__(16) char smA [128 * 128];   // bf16 128r x 64K
    __shared__ __align__(16) char smBg[64 * 256];    // fp32 64c x 64K
    __shared__ __align__(16) char smBu[64 * 256];
    __shared__ int sTok[128];

    const int t = threadIdx.x;
    const int lane = t & 63;
    const int wv = t >> 6;
    const int wr = wv >> 1, wc = wv & 1;
    if (t < 128) sTok[t] = perm_slot[min(p0 + t, NKROWS - 1)] >> 1;
    __syncthreads();

    // A-DMA: chunk ch=wv*4+c covers rows ch*8 .. +8 (128B each)
    const char* asrc[4];
    int aldo[4];
#pragma unroll
    for (int c = 0; c < 4; ++c) {
        int ch = wv * 4 + c;
        int rin = lane >> 3;                 // row within chunk = (row&7)
        int row = ch * 8 + rin;
        asrc[c] = (const char*)(hbf + (size_t)sTok[row] * HDIM)
                + ((((lane & 7) << 4) ^ (rin << 4)));
        aldo[c] = ch * 1024;
    }
    // B-DMA: chunk ch covers 4 fp32 rows (256B each)
    const float* guE = gu + (size_t)e * (2 * FDIM) * HDIM;
    const char* gsrc[4];
    const char* usrc[4];
    int bldo[4];
#pragma unroll
    for (int c = 0; c < 4; ++c) {
        int ch = wv * 4 + c;
        int row = ch * 4 + (lane >> 4);
        int pre = ((lane & 15) << 4) ^ ((row & 7) << 4);
        gsrc[c] = (const char*)(guE + (size_t)(c0 + row) * HDIM) + pre;
        usrc[c] = (const char*)(guE + (size_t)(FDIM + c0 + row) * HDIM) + pre;
        bldo[c] = ch * 1024;
    }

    floatx4 accg[4][2], accu[4][2];
#pragma unroll
    for (int m = 0; m < 4; ++m)
#pragma unroll
        for (int nn = 0; nn < 2; ++nn) { accg[m][nn] = (floatx4)0.f; accu[m][nn] = (floatx4)0.f; }

    for (int k0 = 0; k0 < HDIM; k0 += 64) {
        if (k0) __syncthreads();             // readers done before overwrite
#pragma unroll
        for (int c = 0; c < 4; ++c) dma16(asrc[c] + (size_t)k0 * 2, smA  + aldo[c]);
#pragma unroll
        for (int c = 0; c < 4; ++c) dma16(gsrc[c] + (size_t)k0 * 4, smBg + bldo[c]);
#pragma unroll
        for (int c = 0; c < 4; ++c) dma16(usrc[c] + (size_t)k0 * 4, smBu + bldo[c]);
        __syncthreads();                     // vmcnt(0) drain -> data visible
#pragma unroll
        for (int kk = 0; kk < 2; ++kk) {
            const int kA = kk * 64 + (lane >> 4) * 16;
            const int kB = kk * 128 + (lane >> 4) * 32;
            bf16x8 a[4], fg[2], fu[2];
#pragma unroll
            for (int m = 0; m < 4; ++m) {
                int row = wr * 64 + m * 16 + (lane & 15);
                a[m] = *reinterpret_cast<const bf16x8*>(smA + row * 128 + (kA ^ ((row & 7) << 4)));
            }
#pragma unroll
            for (int nn = 0; nn < 2; ++nn) {
                int cc = wc * 32 + nn * 16 + (lane & 15);
                int b0 = cc * 256 + (kB ^ ((cc & 7) << 4));
                int b1 = cc * 256 + ((kB + 16) ^ ((cc & 7) << 4));
                fg[nn] = cvt8(*reinterpret_cast<const float4*>(smBg + b0),
                              *reinterpret_cast<const float4*>(smBg + b1));
                fu[nn] = cvt8(*reinterpret_cast<const float4*>(smBu + b0),
                              *reinterpret_cast<const float4*>(smBu + b1));
            }
#pragma unroll
            for (int m = 0; m < 4; ++m)
#pragma unroll
                for (int nn = 0; nn < 2; ++nn) {
                    accg[m][nn] = __builtin_amdgcn_mfma_f32_16x16x32_bf16(a[m], fg[nn], accg[m][nn], 0, 0, 0);
                    accu[m][nn] = __builtin_amdgcn_mfma_f32_16x16x32_bf16(a[m], fu[nn], accu[m][nn], 0, 0, 0);
                }
        }
    }

    // epilogue: silu(gate) * up -> act (bf16)
#pragma unroll
    for (int m = 0; m < 4; ++m)
#pragma unroll
        for (int nn = 0; nn < 2; ++nn)
#pragma unroll
            for (int j = 0; j < 4; ++j) {
                int rr = wr * 64 + m * 16 + ((lane >> 4) << 2) + j;
                if (rr < nr) {
                    int f = c0 + wc * 32 + nn * 16 + (lane & 15);
                    float gg = accg[m][nn][j];
                    float uu = accu[m][nn][j];
                    float s = gg / (1.f + __expf(-gg));
                    act[(size_t)(p0 + rr) * FDIM + f] = f2bf(s * uu);
                }
            }
}

// ---------------------------------------------------------------------------
// GEMM2: partial[slot][h] = w * (act_row . dp[e][h][:]), bf16 output.
// Tile 128 rows x 64 h-cols, same structure as GEMM1 with a single B.
__global__ __launch_bounds__(256, 4) void k_gemm2(
    const unsigned short* __restrict__ act, const float* __restrict__ dp,
    const int* __restrict__ offsets, const int* __restrict__ perm_slot,
    const int* __restrict__ tile_e, const int* __restrict__ tile_rt,
    const float* __restrict__ row_w, unsigned short* __restrict__ partial)
{
    const int e = tile_e[blockIdx.y];
    if (e < 0) return;
    const int rt = tile_rt[blockIdx.y];
    const int off_e = offsets[e];
    const int n_e   = offsets[e + 1] - off_e;
    const int p0 = off_e + rt * 128;
    const int nr = min(128, n_e - rt * 128);
    const int c0 = blockIdx.x * 64;

    __shared__ __align__(16) char smA[128 * 128];
    __shared__ __align__(16) char smB[64 * 256];
    __shared__ int   sSlot[128];
    __shared__ float sW[128];

    const int t = threadIdx.x;
    const int lane = t & 63;
    const int wv = t >> 6;
    const int wr = wv >> 1, wc = wv & 1;
    if (t < 128) {
        int p = min(p0 + t, NKROWS - 1);
        sSlot[t] = perm_slot[p];
        sW[t]    = row_w[p];
    }

    const char* asrc[4];
    int aldo[4];
#pragma unroll
    for (int c = 0; c < 4; ++c) {
        int ch = wv * 4 + c;
        int rin = lane >> 3;
        int row = ch * 8 + rin;
        int p = min(p0 + row, NKROWS - 1);
        asrc[c] = (const char*)(act + (size_t)p * FDIM)
                + ((((lane & 7) << 4) ^ (rin << 4)));
        aldo[c] = ch * 1024;
    }
    const float* dpE = dp + (size_t)e * HDIM * FDIM;
    const char* bsrc[4];
    int bldo[4];
#pragma unroll
    for (int c = 0; c < 4; ++c) {
        int ch = wv * 4 + c;
        int row = ch * 4 + (lane >> 4);
        int pre = ((lane & 15) << 4) ^ ((row & 7) << 4);
        bsrc[c] = (const char*)(dpE + (size_t)(c0 + row) * FDIM) + pre;
        bldo[c] = ch * 1024;
    }

    floatx4 acc[4][2];
#pragma unroll
    for (int m = 0; m < 4; ++m)
#pragma unroll
        for (int nn = 0; nn < 2; ++nn) acc[m][nn] = (floatx4)0.f;

    for (int k0 = 0; k0 < FDIM; k0 += 64) {
        __syncthreads();                     // also covers sSlot/sW fill
#pragma unroll
        for (int c = 0; c < 4; ++c) dma16(asrc[c] + (size_t)k0 * 2, smA + aldo[c]);
#pragma unroll
        for (int c = 0; c < 4; ++c) dma16(bsrc[c] + (size_t)k0 * 4, smB + bldo[c]);
        __syncthreads();
#pragma unroll
        for (int kk = 0; kk < 2; ++kk) {
            const int kA = kk * 64 + (lane >> 4) * 16;
            const int kB = kk * 128 + (lane >> 4) * 32;
            bf16x8 a[4], fb[2];
#pragma unroll
            for (int m = 0; m < 4; ++m) {
                int row = wr * 64 + m * 16 + (lane & 15);
                a[m] = *reinterpret_cast<const bf16x8*>(smA + row * 128 + (kA ^ ((row & 7) << 4)));
            }
#pragma unroll
            for (int nn = 0; nn < 2; ++nn) {
                int cc = wc * 32 + nn * 16 + (lane & 15);
                int b0 = cc * 256 + (kB ^ ((cc & 7) << 4));
                int b1 = cc * 256 + ((kB + 16) ^ ((cc & 7) << 4));
                fb[nn] = cvt8(*reinterpret_cast<const float4*>(smB + b0),
                              *reinterpret_cast<const float4*>(smB + b1));
            }
#pragma unroll
            for (int m = 0; m < 4; ++m)
#pragma unroll
                for (int nn = 0; nn < 2; ++nn)
                    acc[m][nn] = __builtin_amdgcn_mfma_f32_16x16x32_bf16(a[m], fb[nn], acc[m][nn], 0, 0, 0);
        }
    }

#pragma unroll
    for (int m = 0; m < 4; ++m)
#pragma unroll
        for (int nn = 0; nn < 2; ++nn)
#pragma unroll
            for (int j = 0; j < 4; ++j) {
                int rr = wr * 64 + m * 16 + ((lane >> 4) << 2) + j;
                if (rr < nr) {
                    int hcol = c0 + wc * 32 + nn * 16 + (lane & 15);
                    partial[(size_t)sSlot[rr] * HDIM + hcol] = f2bf(sW[rr] * acc[m][nn][j]);
                }
            }
}

// ---------------------------------------------------------------------------
// out[n][h] = partial[2n][h] + partial[2n+1][h]  (bf16 -> fp32)
__global__ __launch_bounds__(256) void k_combine(
    const unsigned short* __restrict__ partial, float* __restrict__ out)
{
    int gid = blockIdx.x * 256 + threadIdx.x;   // NTOK * H / 8 = 262144
    int n = gid >> 7;
    int r = gid & 127;                           // 8-elem group within row
    uint4 a = reinterpret_cast<const uint4*>(partial + (size_t)(2 * n) * HDIM)[r];
    uint4 b = reinterpret_cast<const uint4*>(partial + (size_t)(2 * n + 1) * HDIM)[r];
    float4 o0, o1;
    o0.x = bf2f(a.x & 0xFFFF) + bf2f(b.x & 0xFFFF);
    o0.y = bf2f(a.x >> 16)    + bf2f(b.x >> 16);
    o0.z = bf2f(a.y & 0xFFFF) + bf2f(b.y & 0xFFFF);
    o0.w = bf2f(a.y >> 16)    + bf2f(b.y >> 16);
    o1.x = bf2f(a.z & 0xFFFF) + bf2f(b.z & 0xFFFF);
    o1.y = bf2f(a.z >> 16)    + bf2f(b.z >> 16);
    o1.z = bf2f(a.w & 0xFFFF) + bf2f(b.w & 0xFFFF);
    o1.w = bf2f(a.w >> 16)    + bf2f(b.w >> 16);
    float4* op = reinterpret_cast<float4*>(out + (size_t)n * HDIM + r * 8);
    op[0] = o0;
    op[1] = o1;
}

// ---------------------------------------------------------------------------
extern "C" void kernel_launch(void* const* d_in, const int* in_sizes, int n_in,
                              void* d_out, int out_size, void* d_ws, size_t ws_size,
                              hipStream_t stream)
{
    const float* h  = (const float*)d_in[0];
    const float* rw = (const float*)d_in[1];
    const float* gu = (const float*)d_in[2];
    const float* dp = (const float*)d_in[3];
    float* out = (float*)d_out;

    char* ws = (char*)d_ws;
    int*            topk_idx  = (int*)   (ws + 0);
    float*          topk_w    = (float*) (ws + 16384);
    int*            offsets   = (int*)   (ws + 32768);
    int*            tile_e    = (int*)   (ws + 33024);
    int*            tile_rt   = (int*)   (ws + 33280);
    int*            perm_slot = (int*)   (ws + 36864);
    float*          row_w     = (float*) (ws + 53248);
    unsigned short* hbf       = (unsigned short*)(ws + (1u << 20));
    unsigned short* act       = (unsigned short*)(ws + (8u << 20));
    unsigned short* partial   = (unsigned short*)(ws + (16u << 20));

    hipLaunchKernelGGL(k_router,     dim3(512), dim3(256), 0, stream, h, rw, hbf, topk_idx, topk_w);
    hipLaunchKernelGGL(k_build_perm, dim3(1),   dim3(256), 0, stream, topk_idx, topk_w, offsets, perm_slot, row_w, tile_e, tile_rt);
    hipLaunchKernelGGL(k_gemm1,      dim3(16, MAXTILES), dim3(256), 0, stream, hbf, gu, offsets, perm_slot, tile_e, tile_rt, act);
    hipLaunchKernelGGL(k_gemm2,      dim3(16, MAXTILES), dim3(256), 0, stream, act, dp, offsets, perm_slot, tile_e, tile_rt, row_w, partial);
    hipLaunchKernelGGL(k_combine,    dim3(1024), dim3(256), 0, stream, partial, out);
}